// Round 3
// baseline (45.333 us; speedup 1.0000x reference)
//
#include <hip/hip_runtime.h>
#include <hip/hip_bf16.h>

#define DD 256
#define NROWS 16384
#define BROWS 32  // rows per block; 4 waves, wave w -> cols 64w..64w+63

typedef float f32x4 __attribute__((ext_vector_type(4)));
typedef __bf16 bf16x4 __attribute__((ext_vector_type(4)));
typedef __bf16 bf16x8 __attribute__((ext_vector_type(8)));

// Load 8 consecutive fp32 and round to a bf16x8 MFMA fragment word.
__device__ __forceinline__ bf16x8 cvt_frag(const float* __restrict__ p) {
  f32x4 lo = *(const f32x4*)p;
  f32x4 hi = *(const f32x4*)(p + 4);
  bf16x8 v;
#pragma unroll
  for (int j = 0; j < 4; ++j) {
    v[j] = (__bf16)lo[j];
    v[4 + j] = (__bf16)hi[j];
  }
  return v;
}

// t_lds byte offset with T2-style XOR swizzle: row-stride 512B would put all
// 16 fragment rows on the same banks; XOR bits 4-6 spreads them 8-wide.
__device__ __forceinline__ int t_off(int trow, int tcol) {
  return trow * (DD * 2) + ((tcol * 2) ^ ((trow & 7) << 4));
}

// ---------------------------------------------------------------------------
// out = x + (x @ Wv^T + bv) @ Wout^T + bout     (exact reduction of the ref:
// uniform softmax over constant neighbor axis -> out = v exactly).
// One kernel: GEMM1 -> t (bf16 via LDS) -> GEMM2, fused epilogue.
// Swapped MFMA operands: acc = mfma(W_frag, x_frag) so lane&15 -> row,
// (lane>>4)*4+reg -> col: reg-quad = 4 consecutive cols -> vector stores.
// ---------------------------------------------------------------------------
__global__ __launch_bounds__(256) void fused_knn(
    const float* __restrict__ x, const float* __restrict__ Wqkv,
    const float* __restrict__ bqkv, const float* __restrict__ Wout,
    const float* __restrict__ bout, float* __restrict__ out) {
  __shared__ __bf16 t_lds[BROWS * DD];  // 16 KiB, swizzled

  const int t = threadIdx.x;
  const int w = t >> 6;  // wave -> column group
  const int l = t & 63;
  const int R0 = blockIdx.x * BROWS;
  const int c0 = w * 64;
  const int lr = l & 15;   // fragment row
  const int g = l >> 4;    // k-group
  const int lk = g * 8;    // k offset

  const float* __restrict__ Wv = Wqkv + 2 * DD * DD;
  const float* __restrict__ bv = bqkv + 2 * DD;

  // x fragments (B-operand), rows R0 + rt*16 + lr; reused across all ct.
  bf16x8 xf[2][8];
#pragma unroll
  for (int rt = 0; rt < 2; ++rt) {
    const float* xr = x + (size_t)(R0 + rt * 16 + lr) * DD + lk;
#pragma unroll
    for (int ks = 0; ks < 8; ++ks) xf[rt][ks] = cvt_frag(xr + ks * 32);
  }

  // GEMM1: t[trow][tcol], trow = R0-local row, tcol = v-feature.
  f32x4 acc1[2][4] = {};
#pragma unroll
  for (int ct = 0; ct < 4; ++ct) {
    const float* wvr = Wv + (size_t)(c0 + ct * 16 + lr) * DD + lk;
#pragma unroll
    for (int ks = 0; ks < 8; ++ks) {
      bf16x8 a = cvt_frag(wvr + ks * 32);
      acc1[0][ct] = __builtin_amdgcn_mfma_f32_16x16x32_bf16(a, xf[0][ks], acc1[0][ct], 0, 0, 0);
      acc1[1][ct] = __builtin_amdgcn_mfma_f32_16x16x32_bf16(a, xf[1][ks], acc1[1][ct], 0, 0, 0);
    }
  }

  // + bv, round to bf16, store t to swizzled LDS (8B writes: 4 consec cols).
#pragma unroll
  for (int rt = 0; rt < 2; ++rt) {
#pragma unroll
    for (int ct = 0; ct < 4; ++ct) {
      const int trow = rt * 16 + lr;
      const int tcol = c0 + ct * 16 + g * 4;
      f32x4 v = acc1[rt][ct] + *(const f32x4*)(bv + tcol);
      bf16x4 tv;
#pragma unroll
      for (int j = 0; j < 4; ++j) tv[j] = (__bf16)v[j];
      *(bf16x4*)((char*)t_lds + t_off(trow, tcol)) = tv;
    }
  }
  __syncthreads();

  // t fragments (B-operand) from LDS: row rt*16+lr, k = lk + ks*32.
  bf16x8 tf[2][8];
#pragma unroll
  for (int rt = 0; rt < 2; ++rt) {
    const int trow = rt * 16 + lr;
#pragma unroll
    for (int ks = 0; ks < 8; ++ks)
      tf[rt][ks] = *(const bf16x8*)((const char*)t_lds + t_off(trow, lk + ks * 32));
  }

  // GEMM2: out = t @ Wout^T.
  f32x4 acc2[2][4] = {};
#pragma unroll
  for (int ct = 0; ct < 4; ++ct) {
    const float* wor = Wout + (size_t)(c0 + ct * 16 + lr) * DD + lk;
#pragma unroll
    for (int ks = 0; ks < 8; ++ks) {
      bf16x8 a = cvt_frag(wor + ks * 32);
      acc2[0][ct] = __builtin_amdgcn_mfma_f32_16x16x32_bf16(a, tf[0][ks], acc2[0][ct], 0, 0, 0);
      acc2[1][ct] = __builtin_amdgcn_mfma_f32_16x16x32_bf16(a, tf[1][ks], acc2[1][ct], 0, 0, 0);
    }
  }

  // Epilogue: out = acc2 + x + bout, fully vectorized (reg-quad = 4 cols).
#pragma unroll
  for (int rt = 0; rt < 2; ++rt) {
#pragma unroll
    for (int ct = 0; ct < 4; ++ct) {
      const int row = R0 + rt * 16 + lr;
      const int col = c0 + ct * 16 + g * 4;
      const size_t idx = (size_t)row * DD + col;
      f32x4 xin = *(const f32x4*)(x + idx);
      f32x4 bo = *(const f32x4*)(bout + col);
      *(f32x4*)(out + idx) = acc2[rt][ct] + xin + bo;
    }
  }
}

extern "C" void kernel_launch(void* const* d_in, const int* in_sizes, int n_in,
                              void* d_out, int out_size, void* d_ws, size_t ws_size,
                              hipStream_t stream) {
  const float* x = (const float*)d_in[0];
  const float* Wqkv = (const float*)d_in[1];
  const float* bqkv = (const float*)d_in[2];
  const float* Wout = (const float*)d_in[3];
  const float* bout = (const float*)d_in[4];
  float* out = (float*)d_out;

  fused_knn<<<NROWS / BROWS, 256, 0, stream>>>(x, Wqkv, bqkv, Wout, bout, out);
}

// Round 4
// 37.888 us; speedup vs baseline: 1.1965x; 1.1965x over previous
//
#include <hip/hip_runtime.h>
#include <hip/hip_bf16.h>

#define DD 256
#define NROWS 16384

typedef float f32x4 __attribute__((ext_vector_type(4)));
typedef __bf16 bf16x4 __attribute__((ext_vector_type(4)));
typedef __bf16 bf16x8 __attribute__((ext_vector_type(8)));

// Load 8 consecutive fp32 and round to a bf16x8 MFMA fragment word.
__device__ __forceinline__ bf16x8 cvt_frag(const float* __restrict__ p) {
  f32x4 lo = *(const f32x4*)p;
  f32x4 hi = *(const f32x4*)(p + 4);
  bf16x8 v;
#pragma unroll
  for (int j = 0; j < 4; ++j) {
    v[j] = (__bf16)lo[j];
    v[4 + j] = (__bf16)hi[j];
  }
  return v;
}

// ---------------------------------------------------------------------------
// K1: Wc[i][:] = Wout[i][:] @ Wv  (bf16), bc[i] = bout[i] + Wout[i][:] @ bv.
// One block per row i. Wave w handles d = w, w+4, ...: acc(4 cols/lane) +=
// wrow[d] (wave-uniform scalar) * Wv[d][4q..4q+3] (coalesced f32x4).
// 64 independent 16B loads per lane -> high MLP; 4-slice LDS reduce.
// ---------------------------------------------------------------------------
__global__ __launch_bounds__(256) void wc_bc_kernel(
    const float* __restrict__ Wqkv, const float* __restrict__ bqkv,
    const float* __restrict__ Wout, const float* __restrict__ bout,
    __bf16* __restrict__ Wc, float* __restrict__ bc) {
  __shared__ f32x4 part[4][64];
  __shared__ float red[4];
  const int i = blockIdx.x;
  const int t = threadIdx.x;
  const int w = t >> 6;  // wave = d-slice
  const int q = t & 63;  // column quad
  const float* __restrict__ Wv = Wqkv + 2 * DD * DD;
  const float* __restrict__ bv = bqkv + 2 * DD;
  const float* __restrict__ wrow = Wout + (size_t)i * DD;

  // bc partial: thread t contributes wrow[t] * bv[t].
  float p = wrow[t] * bv[t];
#pragma unroll
  for (int off = 32; off > 0; off >>= 1) p += __shfl_down(p, off);
  if ((t & 63) == 0) red[w] = p;

  f32x4 acc = {0.f, 0.f, 0.f, 0.f};
#pragma unroll 8
  for (int d = w; d < DD; d += 4) {
    const float s = wrow[d];  // wave-uniform -> scalar load
    f32x4 wv = *(const f32x4*)(Wv + (size_t)d * DD + q * 4);
    acc += wv * s;
  }
  part[w][q] = acc;
  __syncthreads();

  if (w == 0) {
    f32x4 s = part[0][q] + part[1][q] + part[2][q] + part[3][q];
    bf16x4 o;
#pragma unroll
    for (int j = 0; j < 4; ++j) o[j] = (__bf16)s[j];
    *(bf16x4*)(Wc + (size_t)i * DD + q * 4) = o;
    if (t == 0) bc[i] = bout[i] + red[0] + red[1] + red[2] + red[3];
  }
}

// ---------------------------------------------------------------------------
// K2: out = x + x @ Wc^T + bc.   M=16384, N=256, K=256, Wc bf16 (L2/L1).
// Block = 256 thr = 4 waves, 16 rows; wave w -> cols 64w..64w+63.
// Grid = 1024 blocks; __launch_bounds__(256,4): VGPR<=128, 4 blocks/CU
// resident (16 waves/CU) -- fixes round-3's 72-VGPR latency serialization.
// Swapped MFMA operands (a=Wc frag, b=x frag): acc reg-quad = 4 consecutive
// out cols -> fully vectorized f32x4 epilogue (validated round 3).
// ---------------------------------------------------------------------------
__global__ __launch_bounds__(256, 4) void knn_attn_main(
    const float* __restrict__ x, const __bf16* __restrict__ Wc,
    const float* __restrict__ bc, float* __restrict__ out) {
  const int t = threadIdx.x;
  const int w = t >> 6;
  const int l = t & 63;
  const int R0 = blockIdx.x * 16;
  const int c0 = w * 64;
  const int lr = l & 15;  // fragment row
  const int g = l >> 4;   // k-group
  const int lk = g * 8;   // k offset

  // x fragments (B operand), fp32 -> bf16 inline. 16 independent 16B loads.
  bf16x8 xf[8];
  const float* xr = x + (size_t)(R0 + lr) * DD + lk;
#pragma unroll
  for (int ks = 0; ks < 8; ++ks) xf[ks] = cvt_frag(xr + ks * 32);

  f32x4 acc[4] = {};
#pragma unroll
  for (int ct = 0; ct < 4; ++ct) {
    const __bf16* wr = Wc + (size_t)(c0 + ct * 16 + lr) * DD + lk;
#pragma unroll
    for (int ks = 0; ks < 8; ++ks) {
      bf16x8 a = *(const bf16x8*)(wr + ks * 32);  // bf16 weights: 16B/lane
      acc[ct] = __builtin_amdgcn_mfma_f32_16x16x32_bf16(a, xf[ks], acc[ct], 0, 0, 0);
    }
  }

  // Epilogue: row = R0+lr, cols = c0+ct*16+g*4 .. +3 (reg-quad = 4 cols).
#pragma unroll
  for (int ct = 0; ct < 4; ++ct) {
    const int col = c0 + ct * 16 + g * 4;
    const size_t idx = (size_t)(R0 + lr) * DD + col;
    f32x4 xin = *(const f32x4*)(x + idx);   // L3-resident re-read
    f32x4 bias = *(const f32x4*)(bc + col); // bc already includes bout
    *(f32x4*)(out + idx) = acc[ct] + xin + bias;
  }
}

extern "C" void kernel_launch(void* const* d_in, const int* in_sizes, int n_in,
                              void* d_out, int out_size, void* d_ws, size_t ws_size,
                              hipStream_t stream) {
  const float* x = (const float*)d_in[0];
  const float* Wqkv = (const float*)d_in[1];
  const float* bqkv = (const float*)d_in[2];
  const float* Wout = (const float*)d_in[3];
  const float* bout = (const float*)d_in[4];
  float* out = (float*)d_out;

  __bf16* Wc = (__bf16*)d_ws;                                   // 128 KiB
  float* bc = (float*)((char*)d_ws + DD * DD * sizeof(__bf16)); // +1 KiB

  wc_bc_kernel<<<DD, 256, 0, stream>>>(Wqkv, bqkv, Wout, bout, Wc, bc);
  knn_attn_main<<<NROWS / 16, 256, 0, stream>>>(x, Wc, bc, out);
}

// Round 5
// 30.975 us; speedup vs baseline: 1.4635x; 1.2232x over previous
//
#include <hip/hip_runtime.h>
#include <hip/hip_bf16.h>

#define DD 256
#define NROWS 16384
#define RPB 16  // rows per K2 block

typedef float f32x4 __attribute__((ext_vector_type(4)));
typedef __bf16 bf16x4 __attribute__((ext_vector_type(4)));
typedef __bf16 bf16x8 __attribute__((ext_vector_type(8)));

// ---------------------------------------------------------------------------
// K1: Wc = Wout @ Wv (bf16), bc = bout + Wout @ bv.
// Grid 1024 = 256 rows x 4 col-groups -> 4 blocks/CU, 16 waves/CU (round-4 K1
// had 1 wave/SIMD: latency fully exposed -- the hidden ~30us kernel).
// Wave w covers d-slice [64w,64w+64); lane q covers one column. All 64 Wv
// loads per lane are independent + coalesced (256B/inst).
// ---------------------------------------------------------------------------
__global__ __launch_bounds__(256) void wc_bc_kernel(
    const float* __restrict__ Wqkv, const float* __restrict__ bqkv,
    const float* __restrict__ Wout, const float* __restrict__ bout,
    __bf16* __restrict__ Wc, float* __restrict__ bc) {
  __shared__ float part[4][64];
  __shared__ float red[4];
  const int b = blockIdx.x;
  const int i = b >> 2;  // Wc row
  const int qc = b & 3;  // column group
  const int t = threadIdx.x;
  const int w = t >> 6;  // d-slice
  const int q = t & 63;  // column within group
  const int c0 = qc * 64;
  const float* __restrict__ Wv = Wqkv + 2 * DD * DD;
  const float* __restrict__ bv = bqkv + 2 * DD;
  const float* __restrict__ wrow = Wout + (size_t)i * DD;

  float acc = 0.f;
  const float* wvp = Wv + (size_t)(w * 64) * DD + c0 + q;
#pragma unroll 8
  for (int dd = 0; dd < 64; ++dd)
    acc += wrow[w * 64 + dd] * wvp[(size_t)dd * DD];  // wrow: s_load (uniform)
  part[w][q] = acc;

  if (qc == 0) {  // bc[i], only one col-group needs it
    const int d = w * 64 + q;
    float p = wrow[d] * bv[d];
#pragma unroll
    for (int off = 32; off > 0; off >>= 1) p += __shfl_down(p, off);
    if (q == 0) red[w] = p;
  }
  __syncthreads();
  if (w == 0) {
    float s = part[0][q] + part[1][q] + part[2][q] + part[3][q];
    Wc[(size_t)i * DD + c0 + q] = (__bf16)s;
    if (qc == 0 && q == 0) bc[i] = bout[i] + red[0] + red[1] + red[2] + red[3];
  }
}

// ---------------------------------------------------------------------------
// K2: out = x + x @ Wc^T + bc.
// x tile (16 rows x 256 f32 = 16KB) reg-staged into XOR-swizzled LDS:
//  - MFMA x-fragments come from conflict-free ds_read_b128 (slot = B/16 ^ r&7)
//  - epilogue residual re-reads EXACT fp32 x from LDS (no 2nd global pass)
// Weights: bf16 Wc from L2, 8 independent loads batched per column-tile.
// Swapped MFMA operands (validated r3/r4): out row = lane&15 (x row),
// out col quad = (lane>>4)*4 + reg -> f32x4 epilogue stores.
// ---------------------------------------------------------------------------
__global__ __launch_bounds__(256, 4) void knn_attn_main(
    const float* __restrict__ x, const __bf16* __restrict__ Wc,
    const float* __restrict__ bc, float* __restrict__ out) {
  __shared__ float xs[RPB * DD];  // 16 KiB, XOR-swizzled (16B granule)

  const int t = threadIdx.x;
  const int w = t >> 6;
  const int l = t & 63;
  const int R0 = blockIdx.x * RPB;
  const int c0 = w * 64;
  const int lr = l & 15;  // fragment row
  const int g = l >> 4;   // k-group
  const int lk = g * 8;   // k offset

  // Stage: thread t loads 64B of row r (coalesced), ds_writes swizzled.
  {
    const int r = t >> 4, c = t & 15;
    const float* src = x + (size_t)(R0 + r) * DD + c * 16;
    f32x4 v0 = *(const f32x4*)(src + 0);
    f32x4 v1 = *(const f32x4*)(src + 4);
    f32x4 v2 = *(const f32x4*)(src + 8);
    f32x4 v3 = *(const f32x4*)(src + 12);
    const int base = r * 1024 + c * 64;
    const int sw = (r & 7) << 4;
    *(f32x4*)((char*)xs + ((base + 0) ^ sw)) = v0;
    *(f32x4*)((char*)xs + ((base + 16) ^ sw)) = v1;
    *(f32x4*)((char*)xs + ((base + 32) ^ sw)) = v2;
    *(f32x4*)((char*)xs + ((base + 48) ^ sw)) = v3;
  }
  __syncthreads();

  // x fragments from LDS, fp32 -> bf16.
  const int rsw = (lr & 7) << 4;
  bf16x8 xf[8];
#pragma unroll
  for (int ks = 0; ks < 8; ++ks) {
    const int b0 = lr * 1024 + (lk + ks * 32) * 4;
    f32x4 lo = *(const f32x4*)((const char*)xs + ((b0 + 0) ^ rsw));
    f32x4 hi = *(const f32x4*)((const char*)xs + ((b0 + 16) ^ rsw));
    bf16x8 v;
#pragma unroll
    for (int j = 0; j < 4; ++j) {
      v[j] = (__bf16)lo[j];
      v[4 + j] = (__bf16)hi[j];
    }
    xf[ks] = v;
  }

  f32x4 acc[4] = {};
#pragma unroll
  for (int ct = 0; ct < 4; ++ct) {
    const __bf16* wr = Wc + (size_t)(c0 + ct * 16 + lr) * DD + lk;
    // 8 independent 16B loads issued before any MFMA consumes them.
    bf16x8 b0 = *(const bf16x8*)(wr + 0 * 32);
    bf16x8 b1 = *(const bf16x8*)(wr + 1 * 32);
    bf16x8 b2 = *(const bf16x8*)(wr + 2 * 32);
    bf16x8 b3 = *(const bf16x8*)(wr + 3 * 32);
    bf16x8 b4 = *(const bf16x8*)(wr + 4 * 32);
    bf16x8 b5 = *(const bf16x8*)(wr + 5 * 32);
    bf16x8 b6 = *(const bf16x8*)(wr + 6 * 32);
    bf16x8 b7 = *(const bf16x8*)(wr + 7 * 32);
    acc[ct] = __builtin_amdgcn_mfma_f32_16x16x32_bf16(b0, xf[0], acc[ct], 0, 0, 0);
    acc[ct] = __builtin_amdgcn_mfma_f32_16x16x32_bf16(b1, xf[1], acc[ct], 0, 0, 0);
    acc[ct] = __builtin_amdgcn_mfma_f32_16x16x32_bf16(b2, xf[2], acc[ct], 0, 0, 0);
    acc[ct] = __builtin_amdgcn_mfma_f32_16x16x32_bf16(b3, xf[3], acc[ct], 0, 0, 0);
    acc[ct] = __builtin_amdgcn_mfma_f32_16x16x32_bf16(b4, xf[4], acc[ct], 0, 0, 0);
    acc[ct] = __builtin_amdgcn_mfma_f32_16x16x32_bf16(b5, xf[5], acc[ct], 0, 0, 0);
    acc[ct] = __builtin_amdgcn_mfma_f32_16x16x32_bf16(b6, xf[6], acc[ct], 0, 0, 0);
    acc[ct] = __builtin_amdgcn_mfma_f32_16x16x32_bf16(b7, xf[7], acc[ct], 0, 0, 0);
  }

  // Epilogue: row = R0+lr, col quad = c0+ct*16+g*4; exact x from LDS.
#pragma unroll
  for (int ct = 0; ct < 4; ++ct) {
    const int col = c0 + ct * 16 + g * 4;
    f32x4 xin = *(const f32x4*)((const char*)xs + ((lr * 1024 + col * 4) ^ rsw));
    f32x4 bias = *(const f32x4*)(bc + col);  // includes bout
    *(f32x4*)(out + (size_t)(R0 + lr) * DD + col) = acc[ct] + xin + bias;
  }
}

extern "C" void kernel_launch(void* const* d_in, const int* in_sizes, int n_in,
                              void* d_out, int out_size, void* d_ws, size_t ws_size,
                              hipStream_t stream) {
  const float* x = (const float*)d_in[0];
  const float* Wqkv = (const float*)d_in[1];
  const float* bqkv = (const float*)d_in[2];
  const float* Wout = (const float*)d_in[3];
  const float* bout = (const float*)d_in[4];
  float* out = (float*)d_out;

  __bf16* Wc = (__bf16*)d_ws;                                   // 128 KiB
  float* bc = (float*)((char*)d_ws + DD * DD * sizeof(__bf16)); // +1 KiB

  wc_bc_kernel<<<4 * DD, 256, 0, stream>>>(Wqkv, bqkv, Wout, bout, Wc, bc);
  knn_attn_main<<<NROWS / RPB, 256, 0, stream>>>(x, Wc, bc, out);
}